// Round 1
// baseline (261.960 us; speedup 1.0000x reference)
//
#include <hip/hip_runtime.h>

// Problem constants: B=8, L=1024, H=512, F=4
// out = gate * [x | alpha @ x],  gate = sigmoid([x|enc] @ W_gate)
// alpha = masked_softmax(max_f(Y_f Y_f^T)),  Y = relu(x @ W_proj)
//
// All GEMMs run as fp16 MFMA (16x16x32) with fp32 accumulate; threshold is
// bf16-scale (8.8e-2) so fp16 precision has ~8x headroom on the softmax path.

typedef _Float16 half8 __attribute__((ext_vector_type(8)));
typedef _Float16 half4 __attribute__((ext_vector_type(4)));
typedef float floatx4 __attribute__((ext_vector_type(4)));

typedef const __attribute__((address_space(1))) void* gas_ptr;
typedef __attribute__((address_space(3))) void* las_ptr;

// ---- shared GEMM tile machinery: BM=BN=128, BK=64, 256 threads (4 waves) ----
// LDS tile layout: row-major [128][64] fp16, 16B groups XOR-swizzled by (row&7)
// so ds_read_b128 fragment loads are <=2-way bank conflicted (free per m136),
// while global_load_lds keeps its required lane-contiguous LDS destinations.

__device__ __forceinline__ void stage_tile(_Float16* lds, const _Float16* src,
                                           int row0, int k0, int ld) {
  int t = threadIdx.x;
#pragma unroll
  for (int p = 0; p < 4; ++p) {
    int c = p * 256 + t;          // chunk 0..1023 (128 rows x 8 groups of 8 elems)
    int row = c >> 3;
    int kg = c & 7;
    int gk = (kg ^ (row & 7)) << 3;
    const _Float16* gp = src + (size_t)(row0 + row) * ld + (k0 + gk);
    __builtin_amdgcn_global_load_lds((gas_ptr)gp, (las_ptr)(lds + c * 8), 16, 0, 0);
  }
}

__device__ __forceinline__ half8 frag_ld(const _Float16* lds, int row, int g) {
  return *(const half8*)(lds + row * 64 + ((g ^ (row & 7)) << 3));
}

// A-operand layout (verified m120): A[m=lane&15][k=quad*8+j]; B symmetric.
__device__ __forceinline__ void mfma_tile(const _Float16* lds_a, const _Float16* lds_b,
                                          floatx4 acc[4][4], int wm, int wn,
                                          int l16, int quad) {
#pragma unroll
  for (int kf = 0; kf < 2; ++kf) {
    half8 af[4], bf[4];
#pragma unroll
    for (int i = 0; i < 4; ++i) af[i] = frag_ld(lds_a, wm * 64 + i * 16 + l16, kf * 4 + quad);
#pragma unroll
    for (int i = 0; i < 4; ++i) bf[i] = frag_ld(lds_b, wn * 64 + i * 16 + l16, kf * 4 + quad);
#pragma unroll
    for (int mi = 0; mi < 4; ++mi)
#pragma unroll
      for (int ni = 0; ni < 4; ++ni)
        acc[mi][ni] = __builtin_amdgcn_mfma_f32_16x16x32_f16(af[mi], bf[ni], acc[mi][ni], 0, 0, 0);
  }
}

#define ZERO_ACC(acc)                                   \
  _Pragma("unroll") for (int mi = 0; mi < 4; ++mi)      \
  _Pragma("unroll") for (int ni = 0; ni < 4; ++ni)      \
  _Pragma("unroll") for (int r = 0; r < 4; ++r) acc[mi][ni][r] = 0.0f;

// ---- pre-pass: casts / transposes ----

__global__ void cast_kernel(const float* __restrict__ in, _Float16* __restrict__ out) {
  int i = blockIdx.x * 256 + threadIdx.x;
  float4 v = ((const float4*)in)[i];
  half4 h;
  h[0] = (_Float16)v.x; h[1] = (_Float16)v.y; h[2] = (_Float16)v.z; h[3] = (_Float16)v.w;
  ((half4*)out)[i] = h;
}

// in (batch,R,C) fp32 -> out (batch,C,R) fp16
__global__ void transpose_cast_kernel(const float* __restrict__ in, _Float16* __restrict__ out,
                                      int R, int C) {
  __shared__ float tile[32][33];
  int c0 = blockIdx.x * 32, r0 = blockIdx.y * 32;
  size_t boff = (size_t)blockIdx.z * R * C;
  in += boff; out += boff;
  int tx = threadIdx.x & 31, ty = threadIdx.x >> 5;  // 32 x 8
#pragma unroll
  for (int i = 0; i < 32; i += 8)
    tile[ty + i][tx] = in[(size_t)(r0 + ty + i) * C + c0 + tx];
  __syncthreads();
#pragma unroll
  for (int i = 0; i < 32; i += 8)
    out[(size_t)(c0 + ty + i) * R + r0 + tx] = (_Float16)tile[tx][ty + i];
}

// ---- K1: y = relu(x @ W_proj + b_proj) -> y_t (B,F,L,H) fp16 ----
// x16 (8192,512), WpT (2048,512); M=8192 N=2048 K=512

__global__ __launch_bounds__(256) void proj_kernel(const _Float16* __restrict__ x16,
                                                   const _Float16* __restrict__ WpT,
                                                   const float* __restrict__ bp,
                                                   _Float16* __restrict__ y_t) {
  __shared__ __align__(16) _Float16 lds_a[128 * 64];
  __shared__ __align__(16) _Float16 lds_b[128 * 64];
  int i0 = blockIdx.y * 128, n0 = blockIdx.x * 128;
  int t = threadIdx.x, lane = t & 63, w = t >> 6;
  int wm = w >> 1, wn = w & 1, quad = lane >> 4, l16 = lane & 15;
  floatx4 acc[4][4];
  ZERO_ACC(acc);
  for (int kt = 0; kt < 8; ++kt) {
    __syncthreads();
    stage_tile(lds_a, x16, i0, kt * 64, 512);
    stage_tile(lds_b, WpT, n0, kt * 64, 512);
    __syncthreads();
    mfma_tile(lds_a, lds_b, acc, wm, wn, l16, quad);
  }
#pragma unroll
  for (int mi = 0; mi < 4; ++mi)
#pragma unroll
    for (int ni = 0; ni < 4; ++ni)
#pragma unroll
      for (int r = 0; r < 4; ++r) {
        int gr = i0 + wm * 64 + mi * 16 + quad * 4 + r;   // 0..8191
        int gc = n0 + wn * 64 + ni * 16 + l16;            // 0..2047
        float c = fmaxf(acc[mi][ni][r] + bp[gc], 0.0f);
        int b = gr >> 10, l = gr & 1023;
        int f = gc & 3, h = gc >> 2;
        y_t[(((size_t)(b * 4 + f)) * 1024 + l) * 512 + h] = (_Float16)c;
      }
}

// ---- K2: S[b,i,j] = max_f sum_h Y_f[i,h] Y_f[j,h] ----

__global__ __launch_bounds__(256) void score_kernel(const _Float16* __restrict__ y_t,
                                                    float* __restrict__ S) {
  __shared__ __align__(16) _Float16 lds_a[128 * 64];
  __shared__ __align__(16) _Float16 lds_b[128 * 64];
  int b = blockIdx.z;
  int i0 = blockIdx.y * 128, j0 = blockIdx.x * 128;
  int t = threadIdx.x, lane = t & 63, w = t >> 6;
  int wm = w >> 1, wn = w & 1, quad = lane >> 4, l16 = lane & 15;
  floatx4 smax[4][4];
#pragma unroll 1
  for (int f = 0; f < 4; ++f) {
    const _Float16* plane = y_t + ((size_t)(b * 4 + f)) * 1024 * 512;
    floatx4 acc[4][4];
    ZERO_ACC(acc);
    for (int kt = 0; kt < 8; ++kt) {
      __syncthreads();
      stage_tile(lds_a, plane, i0, kt * 64, 512);
      stage_tile(lds_b, plane, j0, kt * 64, 512);
      __syncthreads();
      mfma_tile(lds_a, lds_b, acc, wm, wn, l16, quad);
    }
    if (f == 0) {
#pragma unroll
      for (int mi = 0; mi < 4; ++mi)
#pragma unroll
        for (int ni = 0; ni < 4; ++ni) smax[mi][ni] = acc[mi][ni];
    } else {
#pragma unroll
      for (int mi = 0; mi < 4; ++mi)
#pragma unroll
        for (int ni = 0; ni < 4; ++ni)
#pragma unroll
          for (int r = 0; r < 4; ++r)
            smax[mi][ni][r] = fmaxf(smax[mi][ni][r], acc[mi][ni][r]);
    }
  }
  float* Sb = S + (size_t)b * 1024 * 1024;
#pragma unroll
  for (int mi = 0; mi < 4; ++mi)
#pragma unroll
    for (int ni = 0; ni < 4; ++ni)
#pragma unroll
      for (int r = 0; r < 4; ++r) {
        int gi = i0 + wm * 64 + mi * 16 + quad * 4 + r;
        int gj = j0 + wn * 64 + ni * 16 + l16;
        Sb[(size_t)gi * 1024 + gj] = smax[mi][ni][r];
      }
}

// ---- K3: allennlp masked softmax per row -> alpha fp16 ----
// p = softmax(logits*m) (masked entries participate as 0), alpha = p*m/(sum(p*m)+1e-13)

__global__ __launch_bounds__(256) void softmax_kernel(const float* __restrict__ S,
                                                      const int* __restrict__ xmask,
                                                      _Float16* __restrict__ alpha) {
  __shared__ float red[16];
  int row = blockIdx.x;               // 0..8191
  int b = row >> 10, l = row & 1023;
  const float* sr = S + (size_t)row * 1024;
  const int* mr = xmask + b * 1024;
  int t = threadIdx.x, lane = t & 63, wid = t >> 6;
  int rm = mr[l];
  float v[4], mm[4];
  float vmax = 0.0f;  // masked entries are exactly 0, so max >= 0 always
#pragma unroll
  for (int q = 0; q < 4; ++q) {
    int i = t + q * 256;
    int m = (rm && mr[i] && (i != l)) ? 1 : 0;
    mm[q] = (float)m;
    v[q] = m ? sr[i] : 0.0f;
    vmax = fmaxf(vmax, v[q]);
  }
  for (int off = 32; off; off >>= 1) vmax = fmaxf(vmax, __shfl_down(vmax, off));
  if (lane == 0) red[wid] = vmax;
  __syncthreads();
  if (t == 0) red[8] = fmaxf(fmaxf(red[0], red[1]), fmaxf(red[2], red[3]));
  __syncthreads();
  vmax = red[8];
  float e[4], E = 0.0f, E2 = 0.0f;
#pragma unroll
  for (int q = 0; q < 4; ++q) {
    e[q] = expf(v[q] - vmax);
    E += e[q];
    E2 += e[q] * mm[q];
  }
  for (int off = 32; off; off >>= 1) {
    E += __shfl_down(E, off);
    E2 += __shfl_down(E2, off);
  }
  if (lane == 0) { red[wid] = E; red[4 + wid] = E2; }
  __syncthreads();
  if (t == 0) {
    red[9] = red[0] + red[1] + red[2] + red[3];
    red[10] = red[4] + red[5] + red[6] + red[7];
  }
  __syncthreads();
  E = red[9]; E2 = red[10];
  // alpha_i = (e_i/E)*m_i / (E2/E + 1e-13) = e_i*m_i / (E2 + 1e-13*E)
  float inv = 1.0f / (E2 + 1e-13f * E);
  _Float16* ar = alpha + (size_t)row * 1024;
#pragma unroll
  for (int q = 0; q < 4; ++q) {
    int i = t + q * 256;
    ar[i] = (_Float16)(e[q] * mm[q] * inv);
  }
}

// ---- K4: enc[b] = alpha[b] @ x[b]  (uses xT (B,H,L) as B-operand) ----

__global__ __launch_bounds__(256) void attn_kernel(const _Float16* __restrict__ alpha,
                                                   const _Float16* __restrict__ xT,
                                                   _Float16* __restrict__ enc) {
  __shared__ __align__(16) _Float16 lds_a[128 * 64];
  __shared__ __align__(16) _Float16 lds_b[128 * 64];
  int b = blockIdx.z;
  int i0 = blockIdx.y * 128, n0 = blockIdx.x * 128;
  const _Float16* A = alpha + (size_t)b * 1024 * 1024;
  const _Float16* Bm = xT + (size_t)b * 512 * 1024;
  int t = threadIdx.x, lane = t & 63, w = t >> 6;
  int wm = w >> 1, wn = w & 1, quad = lane >> 4, l16 = lane & 15;
  floatx4 acc[4][4];
  ZERO_ACC(acc);
  for (int kt = 0; kt < 16; ++kt) {
    __syncthreads();
    stage_tile(lds_a, A, i0, kt * 64, 1024);
    stage_tile(lds_b, Bm, n0, kt * 64, 1024);
    __syncthreads();
    mfma_tile(lds_a, lds_b, acc, wm, wn, l16, quad);
  }
  _Float16* eb = enc + (size_t)b * 1024 * 512;
#pragma unroll
  for (int mi = 0; mi < 4; ++mi)
#pragma unroll
    for (int ni = 0; ni < 4; ++ni)
#pragma unroll
      for (int r = 0; r < 4; ++r) {
        int gr = i0 + wm * 64 + mi * 16 + quad * 4 + r;  // l
        int gc = n0 + wn * 64 + ni * 16 + l16;           // h
        eb[(size_t)gr * 512 + gc] = (_Float16)acc[mi][ni][r];
      }
}

// ---- K5: gate = sigmoid([x|enc] @ W_gate + b_gate); out = gate*[x|enc] ----

__global__ __launch_bounds__(256) void gate_kernel(const _Float16* __restrict__ x16,
                                                   const _Float16* __restrict__ enc,
                                                   const _Float16* __restrict__ WgT,
                                                   const float* __restrict__ bg,
                                                   const float* __restrict__ x,
                                                   float* __restrict__ out) {
  __shared__ __align__(16) _Float16 lds_a[128 * 64];
  __shared__ __align__(16) _Float16 lds_b[128 * 64];
  int i0 = blockIdx.y * 128, n0 = blockIdx.x * 128;
  int t = threadIdx.x, lane = t & 63, w = t >> 6;
  int wm = w >> 1, wn = w & 1, quad = lane >> 4, l16 = lane & 15;
  floatx4 acc[4][4];
  ZERO_ACC(acc);
  for (int kt = 0; kt < 16; ++kt) {
    __syncthreads();
    if (kt < 8) stage_tile(lds_a, x16, i0, kt * 64, 512);
    else        stage_tile(lds_a, enc, i0, (kt - 8) * 64, 512);
    stage_tile(lds_b, WgT, n0, kt * 64, 1024);
    __syncthreads();
    mfma_tile(lds_a, lds_b, acc, wm, wn, l16, quad);
  }
#pragma unroll
  for (int mi = 0; mi < 4; ++mi)
#pragma unroll
    for (int ni = 0; ni < 4; ++ni)
#pragma unroll
      for (int r = 0; r < 4; ++r) {
        int gr = i0 + wm * 64 + mi * 16 + quad * 4 + r;  // 0..8191
        int gc = n0 + wn * 64 + ni * 16 + l16;           // 0..1023
        float c = acc[mi][ni][r] + bg[gc];
        float g = 1.0f / (1.0f + expf(-c));
        float jv = (gc < 512) ? x[(size_t)gr * 512 + gc]
                              : (float)enc[(size_t)gr * 512 + (gc - 512)];
        out[(size_t)gr * 1024 + gc] = g * jv;
      }
}

// ---- launch ----

extern "C" void kernel_launch(void* const* d_in, const int* in_sizes, int n_in,
                              void* d_out, int out_size, void* d_ws, size_t ws_size,
                              hipStream_t stream) {
  const float* x  = (const float*)d_in[0];   // (8,1024,512)
  const int* xm   = (const int*)d_in[1];     // (8,1024)
  const float* Wp = (const float*)d_in[2];   // (512,2048)
  const float* bp = (const float*)d_in[3];   // (2048)
  const float* Wg = (const float*)d_in[4];   // (1024,1024)
  const float* bg = (const float*)d_in[5];   // (1024)
  float* out = (float*)d_out;

  char* ws = (char*)d_ws;
  const size_t MB = 1024 * 1024;
  _Float16* x16 = (_Float16*)(ws);            // 8 MB  (8192,512)
  _Float16* xT  = (_Float16*)(ws + 8 * MB);   // 8 MB  (8,512,1024)
  _Float16* WpT = (_Float16*)(ws + 16 * MB);  // 2 MB  (2048,512)
  _Float16* WgT = (_Float16*)(ws + 18 * MB);  // 2 MB  (1024,1024)
  _Float16* y_t = (_Float16*)(ws + 20 * MB);  // 32 MB (8,4,1024,512)
  float*    S   = (float*)(ws + 52 * MB);     // 32 MB (8,1024,1024)  [end: 84 MB]
  // y_t is dead after score_kernel: alias alpha/enc onto it
  _Float16* alpha = (_Float16*)(ws + 20 * MB); // 16 MB (8,1024,1024)
  _Float16* enc   = (_Float16*)(ws + 36 * MB); // 8 MB  (8,1024,512)

  cast_kernel<<<4096, 256, 0, stream>>>(x, x16);
  transpose_cast_kernel<<<dim3(16, 32, 8), 256, 0, stream>>>(x, xT, 1024, 512);
  transpose_cast_kernel<<<dim3(64, 16, 1), 256, 0, stream>>>(Wp, WpT, 512, 2048);
  transpose_cast_kernel<<<dim3(32, 32, 1), 256, 0, stream>>>(Wg, WgT, 1024, 1024);

  proj_kernel<<<dim3(16, 64), 256, 0, stream>>>(x16, WpT, bp, y_t);
  score_kernel<<<dim3(8, 8, 8), 256, 0, stream>>>(y_t, S);
  softmax_kernel<<<8192, 256, 0, stream>>>(S, xm, alpha);
  attn_kernel<<<dim3(4, 8, 8), 256, 0, stream>>>(alpha, xT, enc);
  gate_kernel<<<dim3(8, 64), 256, 0, stream>>>(x16, enc, WgT, bg, x, out);
}